// Round 2
// baseline (565.280 us; speedup 1.0000x reference)
//
#include <hip/hip_runtime.h>

#define N_NODES 50000
#define N_EDGES 800000
#define N_GRAPHS 256
#define DIM 128

// ---------------- histogram of dst ----------------
__global__ __launch_bounds__(256) void hist_kernel(const int* __restrict__ dst,
                                                   int* __restrict__ cnt) {
    int e = blockIdx.x * 256 + threadIdx.x;
    if (e < N_EDGES) atomicAdd(&cnt[dst[e]], 1);
}

// ---------------- exclusive scan (single block) ----------------
// rowptr[0..N_NODES], cursor copy, dinv = rsqrt(indeg+1)
#define SCAN_T 1024
#define SCAN_C 49
__global__ __launch_bounds__(1024) void scan_kernel(const int* __restrict__ cnt,
                                                    int* __restrict__ rowptr,
                                                    int* __restrict__ cursor,
                                                    float* __restrict__ dinv) {
    __shared__ int s[SCAN_T];
    int t = threadIdx.x;
    int base = t * SCAN_C;
    int local = 0;
    for (int j = 0; j < SCAN_C; ++j) {
        int idx = base + j;
        local += (idx < N_NODES) ? cnt[idx] : 0;
    }
    s[t] = local;
    __syncthreads();
    for (int d = 1; d < SCAN_T; d <<= 1) {
        int v = s[t];
        if (t >= d) v += s[t - d];
        __syncthreads();
        s[t] = v;
        __syncthreads();
    }
    int run = (t == 0) ? 0 : s[t - 1];
    for (int j = 0; j < SCAN_C; ++j) {
        int idx = base + j;
        if (idx < N_NODES) {
            int c = cnt[idx];
            rowptr[idx] = run;
            cursor[idx] = run;
            dinv[idx] = rsqrtf((float)(c + 1));
            run += c;
        } else if (idx == N_NODES) {
            rowptr[idx] = run;
        }
    }
}

// ---------------- scatter edges into CSR ----------------
__global__ __launch_bounds__(256) void scatter_kernel(const int* __restrict__ src,
                                                      const int* __restrict__ dst,
                                                      int* __restrict__ cursor,
                                                      int* __restrict__ ssrc) {
    int e = blockIdx.x * 256 + threadIdx.x;
    if (e < N_EDGES) {
        int d = dst[e];
        int pos = atomicAdd(&cursor[d], 1);
        ssrc[pos] = src[e];
    }
}

// ---------------- Y[n,128] = X[n,128] @ W[128,128] (fp32) ----------------
__global__ __launch_bounds__(256) void mm128_kernel(const float* __restrict__ X,
                                                    const float* __restrict__ W,
                                                    float* __restrict__ Y, int nrows) {
    __shared__ float Ws[128 * 128];   // 64 KB
    __shared__ float Xs[32 * 128];    // 16 KB
    const float4* W4 = (const float4*)W;
    float4* Ws4 = (float4*)Ws;
    for (int i = threadIdx.x; i < 4096; i += 256) Ws4[i] = W4[i];

    const float4* X4 = (const float4*)X;
    float4* Xs4 = (float4*)Xs;
    float4* Y4 = (float4*)Y;
    int ntiles = (nrows + 31) >> 5;
    for (int tile = blockIdx.x; tile < ntiles; tile += gridDim.x) {
        int r0 = tile << 5;
        __syncthreads();
        for (int i = threadIdx.x; i < 1024; i += 256) {
            int row = i >> 5, q = i & 31;
            int gr = r0 + row;
            Xs4[i] = (gr < nrows) ? X4[gr * 32 + q] : make_float4(0.f, 0.f, 0.f, 0.f);
        }
        __syncthreads();
        int grp = threadIdx.x >> 5;   // 0..7 -> 4 rows each
        int l32 = threadIdx.x & 31;   // col quad
        float4 a0 = {0, 0, 0, 0}, a1 = a0, a2 = a0, a3 = a0;
#pragma unroll 4
        for (int k = 0; k < 128; ++k) {
            float4 w = Ws4[k * 32 + l32];
            float x0 = Xs[(grp * 4 + 0) * 128 + k];
            float x1 = Xs[(grp * 4 + 1) * 128 + k];
            float x2 = Xs[(grp * 4 + 2) * 128 + k];
            float x3 = Xs[(grp * 4 + 3) * 128 + k];
            a0.x += x0 * w.x; a0.y += x0 * w.y; a0.z += x0 * w.z; a0.w += x0 * w.w;
            a1.x += x1 * w.x; a1.y += x1 * w.y; a1.z += x1 * w.z; a1.w += x1 * w.w;
            a2.x += x2 * w.x; a2.y += x2 * w.y; a2.z += x2 * w.z; a2.w += x2 * w.w;
            a3.x += x3 * w.x; a3.y += x3 * w.y; a3.z += x3 * w.z; a3.w += x3 * w.w;
        }
        int rb = r0 + grp * 4;
        if (rb + 0 < nrows) Y4[(rb + 0) * 32 + l32] = a0;
        if (rb + 1 < nrows) Y4[(rb + 1) * 32 + l32] = a1;
        if (rb + 2 < nrows) Y4[(rb + 2) * 32 + l32] = a2;
        if (rb + 3 < nrows) Y4[(rb + 3) * 32 + l32] = a3;
    }
}

// ---------------- aggregation: one wave per node ----------------
__global__ __launch_bounds__(256) void agg_kernel(const float* __restrict__ H,
                                                  const int* __restrict__ rowptr,
                                                  const int* __restrict__ ssrc,
                                                  const float* __restrict__ dinv,
                                                  const float* __restrict__ bias,
                                                  float* __restrict__ O) {
    int gw = (int)((blockIdx.x * 256 + threadIdx.x) >> 6);
    if (gw >= N_NODES) return;
    int v = __builtin_amdgcn_readfirstlane(gw);   // force SGPR -> s_loads for row data
    int lane = threadIdx.x & 63;
    const float2* H2 = (const float2*)H;
    float dv = dinv[v];
    float2 hv = H2[(size_t)v * 64 + lane];
    float sc = dv * dv;
    float a0 = hv.x * sc, a1 = hv.y * sc;
    int e = rowptr[v], eend = rowptr[v + 1];
    for (; e + 4 <= eend; e += 4) {
        int s0 = ssrc[e], s1 = ssrc[e + 1], s2 = ssrc[e + 2], s3 = ssrc[e + 3];
        float w0 = dinv[s0] * dv, w1 = dinv[s1] * dv, w2 = dinv[s2] * dv, w3 = dinv[s3] * dv;
        float2 h0 = H2[(size_t)s0 * 64 + lane];
        float2 h1 = H2[(size_t)s1 * 64 + lane];
        float2 h2 = H2[(size_t)s2 * 64 + lane];
        float2 h3 = H2[(size_t)s3 * 64 + lane];
        a0 += w0 * h0.x + w1 * h1.x + w2 * h2.x + w3 * h3.x;
        a1 += w0 * h0.y + w1 * h1.y + w2 * h2.y + w3 * h3.y;
    }
    for (; e < eend; ++e) {
        int s = ssrc[e];
        float w = dinv[s] * dv;
        float2 hs = H2[(size_t)s * 64 + lane];
        a0 += w * hs.x;
        a1 += w * hs.y;
    }
    float2 b2 = ((const float2*)bias)[lane];
    float2 o;
    o.x = fmaxf(a0 + b2.x, 0.f);
    o.y = fmaxf(a1 + b2.y, 0.f);
    ((float2*)O)[(size_t)v * 64 + lane] = o;
}

// ---------------- mean pool per graph (batch is sorted) ----------------
__device__ __forceinline__ int lbound(const int* __restrict__ a, int n, int v) {
    int lo = 0, hi = n;
    while (lo < hi) {
        int mid = (lo + hi) >> 1;
        if (a[mid] < v) lo = mid + 1; else hi = mid;
    }
    return lo;
}

__global__ __launch_bounds__(512) void pool_kernel(const float* __restrict__ H,
                                                   const int* __restrict__ batch,
                                                   float* __restrict__ P) {
    int g = blockIdx.x;
    __shared__ int sse[2];
    __shared__ float red[512];
    if (threadIdx.x < 2) sse[threadIdx.x] = lbound(batch, N_NODES, g + threadIdx.x);
    __syncthreads();
    int ss = sse[0], se = sse[1];
    int d = threadIdx.x & 127, c = threadIdx.x >> 7;
    float sum = 0.f;
    for (int n = ss + c; n < se; n += 4) sum += H[(size_t)n * 128 + d];
    red[threadIdx.x] = sum;
    __syncthreads();
    if (threadIdx.x < 128) {
        float s = red[threadIdx.x] + red[threadIdx.x + 128] + red[threadIdx.x + 256] + red[threadIdx.x + 384];
        float cntf = (float)(se - ss);
        P[g * 128 + threadIdx.x] = s / fmaxf(cntf, 1.f);
    }
}

// ---------------- MLP + log_softmax ----------------
__global__ __launch_bounds__(128) void mlp_kernel(const float* __restrict__ P1,
                                                  const float* __restrict__ P2,
                                                  const float* __restrict__ L1W,
                                                  const float* __restrict__ L1b,
                                                  const float* __restrict__ L2W,
                                                  const float* __restrict__ L2b,
                                                  float* __restrict__ out) {
    int g = blockIdx.x, j = threadIdx.x;
    __shared__ float gv[256];
    __shared__ float hid[128];
    gv[j] = P1[g * 128 + j];
    gv[128 + j] = P2[g * 128 + j];
    __syncthreads();
    float acc = L1b[j];
#pragma unroll 8
    for (int k = 0; k < 256; ++k) acc = fmaf(gv[k], L1W[k * 128 + j], acc);
    hid[j] = fmaxf(acc, 0.f);
    __syncthreads();
    if (j == 0) {
        float o0 = L2b[0], o1 = L2b[1];
        for (int k = 0; k < 128; ++k) {
            o0 += hid[k] * L2W[2 * k + 0];
            o1 += hid[k] * L2W[2 * k + 1];
        }
        float m = fmaxf(o0, o1);
        float lse = m + logf(expf(o0 - m) + expf(o1 - m));
        out[g * 2 + 0] = o0 - lse;
        out[g * 2 + 1] = o1 - lse;
    }
}

extern "C" void kernel_launch(void* const* d_in, const int* in_sizes, int n_in,
                              void* d_out, int out_size, void* d_ws, size_t ws_size,
                              hipStream_t stream) {
    const float* x    = (const float*)d_in[0];
    const int*   ei   = (const int*)d_in[1];    // [2, N_EDGES]: src row then dst row
    const int*   batch= (const int*)d_in[2];
    const float* W1   = (const float*)d_in[3];
    const float* b1   = (const float*)d_in[4];
    const float* W2   = (const float*)d_in[5];
    const float* b2   = (const float*)d_in[6];
    const float* L1W  = (const float*)d_in[7];
    const float* L1b  = (const float*)d_in[8];
    const float* L2W  = (const float*)d_in[9];
    const float* L2b  = (const float*)d_in[10];
    float* out = (float*)d_out;

    const int* e_src = ei;
    const int* e_dst = ei + N_EDGES;

    char* ws = (char*)d_ws;
    size_t off = 0;
    auto alloc = [&](size_t bytes) {
        void* p = ws + off;
        off += (bytes + 255) & ~(size_t)255;
        return p;
    };
    int*   deg_cnt   = (int*)alloc(N_NODES * 4);
    int*   rowptr    = (int*)alloc((N_NODES + 1) * 4);
    int*   cursor    = (int*)alloc(N_NODES * 4);
    int*   ssrc      = (int*)alloc(N_EDGES * 4);
    float* dinv      = (float*)alloc(N_NODES * 4);
    float* p1        = (float*)alloc(N_GRAPHS * DIM * 4);
    float* p2        = (float*)alloc(N_GRAPHS * DIM * 4);
    float* bufA      = (float*)alloc((size_t)N_NODES * DIM * 4);
    float* bufB      = (float*)alloc((size_t)N_NODES * DIM * 4);
    (void)ws_size; (void)in_sizes; (void)n_in; (void)out_size;

    hipMemsetAsync(deg_cnt, 0, N_NODES * 4, stream);

    const int EB = (N_EDGES + 255) / 256;      // 3125
    hist_kernel<<<EB, 256, 0, stream>>>(e_dst, deg_cnt);
    scan_kernel<<<1, 1024, 0, stream>>>(deg_cnt, rowptr, cursor, dinv);
    scatter_kernel<<<EB, 256, 0, stream>>>(e_src, e_dst, cursor, ssrc);

    const int MMB = (N_NODES + 31) / 32;       // 1563
    const int AGB = (N_NODES * 64 + 255) / 256; // 12500

    // conv1
    mm128_kernel<<<MMB, 256, 0, stream>>>(x, W1, bufA, N_NODES);
    agg_kernel<<<AGB, 256, 0, stream>>>(bufA, rowptr, ssrc, dinv, b1, bufB);  // h1
    pool_kernel<<<N_GRAPHS, 512, 0, stream>>>(bufB, batch, p1);

    // conv2
    mm128_kernel<<<MMB, 256, 0, stream>>>(bufB, W2, bufA, N_NODES);
    agg_kernel<<<AGB, 256, 0, stream>>>(bufA, rowptr, ssrc, dinv, b2, bufB);  // h2 overwrites h1
    pool_kernel<<<N_GRAPHS, 512, 0, stream>>>(bufB, batch, p2);

    // head
    mlp_kernel<<<N_GRAPHS, 128, 0, stream>>>(p1, p2, L1W, L1b, L2W, L2b, out);
}

// Round 3
// 414.825 us; speedup vs baseline: 1.3627x; 1.3627x over previous
//
#include <hip/hip_runtime.h>

#define N_NODES 50000
#define N_EDGES 800000
#define N_GRAPHS 256
#define DIM 128

#define SCAN_B 1024
#define SCAN_NB 49   // ceil(50000/1024)

// ---------------- histogram of dst ----------------
__global__ __launch_bounds__(256) void hist_kernel(const int* __restrict__ dst,
                                                   int* __restrict__ cnt) {
    int e = blockIdx.x * 256 + threadIdx.x;
    if (e < N_EDGES) atomicAdd(&cnt[dst[e]], 1);
}

// ---------------- 3-phase parallel exclusive scan ----------------
// Phase 1: per-block sums
__global__ __launch_bounds__(SCAN_B) void reduce_kernel(const int* __restrict__ cnt,
                                                        int* __restrict__ blocksum) {
    __shared__ int red[SCAN_B / 64];
    int idx = blockIdx.x * SCAN_B + threadIdx.x;
    int v = (idx < N_NODES) ? cnt[idx] : 0;
    // wave reduce
    for (int d = 32; d >= 1; d >>= 1) v += __shfl_down(v, d, 64);
    int wid = threadIdx.x >> 6;
    if ((threadIdx.x & 63) == 0) red[wid] = v;
    __syncthreads();
    if (threadIdx.x == 0) {
        int s = 0;
        for (int w = 0; w < SCAN_B / 64; ++w) s += red[w];
        blocksum[blockIdx.x] = s;
    }
}

// Phase 2: exclusive scan of the 49 block sums (single tiny block)
__global__ __launch_bounds__(64) void scanblk_kernel(int* __restrict__ blocksum) {
    __shared__ int s[64];
    int t = threadIdx.x;
    s[t] = (t < SCAN_NB) ? blocksum[t] : 0;
    __syncthreads();
    if (t == 0) {
        int run = 0;
        for (int i = 0; i < SCAN_NB; ++i) {
            int c = s[i];
            blocksum[i] = run;   // exclusive offsets in-place
            run += c;
        }
    }
}

// Phase 3: block-local exclusive scan + offset; emit rowptr/cursor/dinv
__global__ __launch_bounds__(SCAN_B) void scanout_kernel(const int* __restrict__ cnt,
                                                         const int* __restrict__ blockoff,
                                                         int* __restrict__ rowptr,
                                                         int* __restrict__ cursor,
                                                         float* __restrict__ dinv) {
    __shared__ int s[SCAN_B];
    int t = threadIdx.x;
    int idx = blockIdx.x * SCAN_B + t;
    int c = (idx < N_NODES) ? cnt[idx] : 0;
    s[t] = c;
    __syncthreads();
    // Hillis-Steele inclusive scan
    for (int d = 1; d < SCAN_B; d <<= 1) {
        int v = s[t];
        if (t >= d) v += s[t - d];
        __syncthreads();
        s[t] = v;
        __syncthreads();
    }
    if (idx < N_NODES) {
        int excl = blockoff[blockIdx.x] + s[t] - c;   // inclusive - self = exclusive
        rowptr[idx] = excl;
        cursor[idx] = excl;
        dinv[idx] = rsqrtf((float)(c + 1));
        if (idx == 0) rowptr[N_NODES] = N_EDGES;      // total is static
    }
}

// ---------------- scatter edges into CSR ----------------
__global__ __launch_bounds__(256) void scatter_kernel(const int* __restrict__ src,
                                                      const int* __restrict__ dst,
                                                      int* __restrict__ cursor,
                                                      int* __restrict__ ssrc) {
    int e = blockIdx.x * 256 + threadIdx.x;
    if (e < N_EDGES) {
        int d = dst[e];
        int pos = atomicAdd(&cursor[d], 1);
        ssrc[pos] = src[e];
    }
}

// ---------------- Y[n,128] = X[n,128] @ W[128,128] (fp32) ----------------
__global__ __launch_bounds__(256) void mm128_kernel(const float* __restrict__ X,
                                                    const float* __restrict__ W,
                                                    float* __restrict__ Y, int nrows) {
    __shared__ float Ws[128 * 128];   // 64 KB
    __shared__ float Xs[32 * 128];    // 16 KB
    const float4* W4 = (const float4*)W;
    float4* Ws4 = (float4*)Ws;
    for (int i = threadIdx.x; i < 4096; i += 256) Ws4[i] = W4[i];

    const float4* X4 = (const float4*)X;
    float4* Xs4 = (float4*)Xs;
    float4* Y4 = (float4*)Y;
    int ntiles = (nrows + 31) >> 5;
    for (int tile = blockIdx.x; tile < ntiles; tile += gridDim.x) {
        int r0 = tile << 5;
        __syncthreads();
        for (int i = threadIdx.x; i < 1024; i += 256) {
            int row = i >> 5, q = i & 31;
            int gr = r0 + row;
            Xs4[i] = (gr < nrows) ? X4[gr * 32 + q] : make_float4(0.f, 0.f, 0.f, 0.f);
        }
        __syncthreads();
        int grp = threadIdx.x >> 5;   // 0..7 -> 4 rows each
        int l32 = threadIdx.x & 31;   // col quad
        float4 a0 = {0, 0, 0, 0}, a1 = a0, a2 = a0, a3 = a0;
#pragma unroll 4
        for (int k = 0; k < 128; ++k) {
            float4 w = Ws4[k * 32 + l32];
            float x0 = Xs[(grp * 4 + 0) * 128 + k];
            float x1 = Xs[(grp * 4 + 1) * 128 + k];
            float x2 = Xs[(grp * 4 + 2) * 128 + k];
            float x3 = Xs[(grp * 4 + 3) * 128 + k];
            a0.x += x0 * w.x; a0.y += x0 * w.y; a0.z += x0 * w.z; a0.w += x0 * w.w;
            a1.x += x1 * w.x; a1.y += x1 * w.y; a1.z += x1 * w.z; a1.w += x1 * w.w;
            a2.x += x2 * w.x; a2.y += x2 * w.y; a2.z += x2 * w.z; a2.w += x2 * w.w;
            a3.x += x3 * w.x; a3.y += x3 * w.y; a3.z += x3 * w.z; a3.w += x3 * w.w;
        }
        int rb = r0 + grp * 4;
        if (rb + 0 < nrows) Y4[(rb + 0) * 32 + l32] = a0;
        if (rb + 1 < nrows) Y4[(rb + 1) * 32 + l32] = a1;
        if (rb + 2 < nrows) Y4[(rb + 2) * 32 + l32] = a2;
        if (rb + 3 < nrows) Y4[(rb + 3) * 32 + l32] = a3;
    }
}

// ---------------- aggregation: one wave per node ----------------
__global__ __launch_bounds__(256) void agg_kernel(const float* __restrict__ H,
                                                  const int* __restrict__ rowptr,
                                                  const int* __restrict__ ssrc,
                                                  const float* __restrict__ dinv,
                                                  const float* __restrict__ bias,
                                                  float* __restrict__ O) {
    int gw = (int)((blockIdx.x * 256 + threadIdx.x) >> 6);
    if (gw >= N_NODES) return;
    int v = __builtin_amdgcn_readfirstlane(gw);   // force SGPR -> s_loads for row data
    int lane = threadIdx.x & 63;
    const float2* H2 = (const float2*)H;
    float dv = dinv[v];
    float2 hv = H2[(size_t)v * 64 + lane];
    float sc = dv * dv;
    float a0 = hv.x * sc, a1 = hv.y * sc;
    int e = rowptr[v], eend = rowptr[v + 1];
    for (; e + 4 <= eend; e += 4) {
        int s0 = ssrc[e], s1 = ssrc[e + 1], s2 = ssrc[e + 2], s3 = ssrc[e + 3];
        float w0 = dinv[s0] * dv, w1 = dinv[s1] * dv, w2 = dinv[s2] * dv, w3 = dinv[s3] * dv;
        float2 h0 = H2[(size_t)s0 * 64 + lane];
        float2 h1 = H2[(size_t)s1 * 64 + lane];
        float2 h2 = H2[(size_t)s2 * 64 + lane];
        float2 h3 = H2[(size_t)s3 * 64 + lane];
        a0 += w0 * h0.x + w1 * h1.x + w2 * h2.x + w3 * h3.x;
        a1 += w0 * h0.y + w1 * h1.y + w2 * h2.y + w3 * h3.y;
    }
    for (; e < eend; ++e) {
        int s = ssrc[e];
        float w = dinv[s] * dv;
        float2 hs = H2[(size_t)s * 64 + lane];
        a0 += w * hs.x;
        a1 += w * hs.y;
    }
    float2 b2 = ((const float2*)bias)[lane];
    float2 o;
    o.x = fmaxf(a0 + b2.x, 0.f);
    o.y = fmaxf(a1 + b2.y, 0.f);
    ((float2*)O)[(size_t)v * 64 + lane] = o;
}

// ---------------- mean pool per graph (batch is sorted) ----------------
__device__ __forceinline__ int lbound(const int* __restrict__ a, int n, int v) {
    int lo = 0, hi = n;
    while (lo < hi) {
        int mid = (lo + hi) >> 1;
        if (a[mid] < v) lo = mid + 1; else hi = mid;
    }
    return lo;
}

__global__ __launch_bounds__(512) void pool_kernel(const float* __restrict__ H,
                                                   const int* __restrict__ batch,
                                                   float* __restrict__ P) {
    int g = blockIdx.x;
    __shared__ int sse[2];
    __shared__ float red[512];
    if (threadIdx.x < 2) sse[threadIdx.x] = lbound(batch, N_NODES, g + threadIdx.x);
    __syncthreads();
    int ss = sse[0], se = sse[1];
    int d = threadIdx.x & 127, c = threadIdx.x >> 7;
    float sum = 0.f;
    for (int n = ss + c; n < se; n += 4) sum += H[(size_t)n * 128 + d];
    red[threadIdx.x] = sum;
    __syncthreads();
    if (threadIdx.x < 128) {
        float s = red[threadIdx.x] + red[threadIdx.x + 128] + red[threadIdx.x + 256] + red[threadIdx.x + 384];
        float cntf = (float)(se - ss);
        P[g * 128 + threadIdx.x] = s / fmaxf(cntf, 1.f);
    }
}

// ---------------- MLP + log_softmax ----------------
__global__ __launch_bounds__(128) void mlp_kernel(const float* __restrict__ P1,
                                                  const float* __restrict__ P2,
                                                  const float* __restrict__ L1W,
                                                  const float* __restrict__ L1b,
                                                  const float* __restrict__ L2W,
                                                  const float* __restrict__ L2b,
                                                  float* __restrict__ out) {
    int g = blockIdx.x, j = threadIdx.x;
    __shared__ float gv[256];
    __shared__ float hid[128];
    gv[j] = P1[g * 128 + j];
    gv[128 + j] = P2[g * 128 + j];
    __syncthreads();
    float acc = L1b[j];
#pragma unroll 8
    for (int k = 0; k < 256; ++k) acc = fmaf(gv[k], L1W[k * 128 + j], acc);
    hid[j] = fmaxf(acc, 0.f);
    __syncthreads();
    if (j == 0) {
        float o0 = L2b[0], o1 = L2b[1];
        for (int k = 0; k < 128; ++k) {
            o0 += hid[k] * L2W[2 * k + 0];
            o1 += hid[k] * L2W[2 * k + 1];
        }
        float m = fmaxf(o0, o1);
        float lse = m + logf(expf(o0 - m) + expf(o1 - m));
        out[g * 2 + 0] = o0 - lse;
        out[g * 2 + 1] = o1 - lse;
    }
}

extern "C" void kernel_launch(void* const* d_in, const int* in_sizes, int n_in,
                              void* d_out, int out_size, void* d_ws, size_t ws_size,
                              hipStream_t stream) {
    const float* x    = (const float*)d_in[0];
    const int*   ei   = (const int*)d_in[1];    // [2, N_EDGES]: src row then dst row
    const int*   batch= (const int*)d_in[2];
    const float* W1   = (const float*)d_in[3];
    const float* b1   = (const float*)d_in[4];
    const float* W2   = (const float*)d_in[5];
    const float* b2   = (const float*)d_in[6];
    const float* L1W  = (const float*)d_in[7];
    const float* L1b  = (const float*)d_in[8];
    const float* L2W  = (const float*)d_in[9];
    const float* L2b  = (const float*)d_in[10];
    float* out = (float*)d_out;

    const int* e_src = ei;
    const int* e_dst = ei + N_EDGES;

    char* ws = (char*)d_ws;
    size_t off = 0;
    auto alloc = [&](size_t bytes) {
        void* p = ws + off;
        off += (bytes + 255) & ~(size_t)255;
        return p;
    };
    int*   deg_cnt   = (int*)alloc(N_NODES * 4);
    int*   rowptr    = (int*)alloc((N_NODES + 1) * 4);
    int*   cursor    = (int*)alloc(N_NODES * 4);
    int*   ssrc      = (int*)alloc(N_EDGES * 4);
    float* dinv      = (float*)alloc(N_NODES * 4);
    int*   blocksum  = (int*)alloc(SCAN_NB * 4);
    float* p1        = (float*)alloc(N_GRAPHS * DIM * 4);
    float* p2        = (float*)alloc(N_GRAPHS * DIM * 4);
    float* bufA      = (float*)alloc((size_t)N_NODES * DIM * 4);
    float* bufB      = (float*)alloc((size_t)N_NODES * DIM * 4);
    (void)ws_size; (void)in_sizes; (void)n_in; (void)out_size;

    hipMemsetAsync(deg_cnt, 0, N_NODES * 4, stream);

    const int EB = (N_EDGES + 255) / 256;      // 3125
    hist_kernel<<<EB, 256, 0, stream>>>(e_dst, deg_cnt);
    reduce_kernel<<<SCAN_NB, SCAN_B, 0, stream>>>(deg_cnt, blocksum);
    scanblk_kernel<<<1, 64, 0, stream>>>(blocksum);
    scanout_kernel<<<SCAN_NB, SCAN_B, 0, stream>>>(deg_cnt, blocksum, rowptr, cursor, dinv);
    scatter_kernel<<<EB, 256, 0, stream>>>(e_src, e_dst, cursor, ssrc);

    const int MMB = (N_NODES + 31) / 32;       // 1563
    const int AGB = (N_NODES * 64 + 255) / 256; // 12500

    // conv1
    mm128_kernel<<<MMB, 256, 0, stream>>>(x, W1, bufA, N_NODES);
    agg_kernel<<<AGB, 256, 0, stream>>>(bufA, rowptr, ssrc, dinv, b1, bufB);  // h1
    pool_kernel<<<N_GRAPHS, 512, 0, stream>>>(bufB, batch, p1);

    // conv2
    mm128_kernel<<<MMB, 256, 0, stream>>>(bufB, W2, bufA, N_NODES);
    agg_kernel<<<AGB, 256, 0, stream>>>(bufA, rowptr, ssrc, dinv, b2, bufB);  // h2 overwrites h1
    pool_kernel<<<N_GRAPHS, 512, 0, stream>>>(bufB, batch, p2);

    // head
    mlp_kernel<<<N_GRAPHS, 128, 0, stream>>>(p1, p2, L1W, L1b, L2W, L2b, out);
}